// Round 10
// baseline (286.355 us; speedup 1.0000x reference)
//
#include <hip/hip_runtime.h>

// ---------------------------------------------------------------------------
// SOABlock: f,g = BN(ReLU(1x1conv)), h = 1x1conv, attn = softmax(f^T g /16),
// z = attn @ h^T, out = v(z) + x.   B=16, C=512, MID=256, N=48*48=2304.
// ---------------------------------------------------------------------------

#define B_    16
#define C_    512
#define MID_  256
#define N_    2304
#define NT_   (B_ * N_)          // 36864

typedef unsigned short u16;
typedef unsigned int   u32;
typedef unsigned long long ull;
typedef short s16x8 __attribute__((ext_vector_type(8)));   // 8 bf16 (4 VGPR)
typedef float f32x4 __attribute__((ext_vector_type(4)));
typedef float f32x16 __attribute__((ext_vector_type(16)));

// exp constants: P = exp(S/16 - 20) = exp2(S*K1F - K2F)
#define K1F 0.09016844005556021f
#define K2F 28.853900817779268f

#define MFMA16(a, b, c) __builtin_amdgcn_mfma_f32_16x16x32_bf16(a, b, c, 0, 0, 0)
#define MFMA32(a, b, c) __builtin_amdgcn_mfma_f32_32x32x16_bf16(a, b, c, 0, 0, 0)

__device__ __forceinline__ u16 f2bf(float f) {
  unsigned int u = __float_as_uint(f);
  return (u16)((u + 0x7FFFu + ((u >> 16) & 1u)) >> 16);
}
__device__ __forceinline__ u32 pack2bf(float a, float b) {
  return (u32)f2bf(a) | ((u32)f2bf(b) << 16);
}
__device__ __forceinline__ ull pack4bf(float a, float b, float c, float d) {
  return (ull)pack2bf(a, b) | ((ull)pack2bf(c, d) << 32);
}
// truncating pack (P values; ~0.2% bias is fine, saves VALU)
__device__ __forceinline__ u32 pack2t(float a, float b) {
  return (__float_as_uint(a) >> 16) | (__float_as_uint(b) & 0xffff0000u);
}
__device__ __forceinline__ float bf2f(u32 v) { return __uint_as_float(v << 16); }
// single-instruction 2^x (avoids libm exp2f guard code in the softmax chain)
__device__ __forceinline__ float fexp2(float x) {
  float r;
  asm("v_exp_f32 %0, %1" : "=v"(r) : "v"(x));
  return r;
}

#define GLL16(src, dst)                                                        \
  __builtin_amdgcn_global_load_lds(                                            \
      (const __attribute__((address_space(1))) void*)(src),                    \
      (__attribute__((address_space(3))) void*)(dst), 16, 0, 0)

// ---------------------------------------------------------------------------
// ws layout (bytes)
#define OFF_XT   0ull            // xT bf16 [36864][512]; later zp splits 0,1
#define OFF_FG   37748736ull     // fg bf16 [36864][512]; later combined z bf16
#define OFF_HT   75497472ull     // hT bf16 [16][256][2304]
#define OFF_WB   94371840ull     // Wfgh bf16 [768][512]
#define OFF_VW   95158272ull     // v_w bf16 [512][256]
#define OFF_BIAS 95420416ull     // bias f32 [768]
#define ZP_ELEMS (9437184ull)    // 36864*256 per split

// ---------------------------------------------------------------------------
// K0: fold BN into conv weights, convert weights to bf16.
__global__ __launch_bounds__(64) void k_prep(
    const float* __restrict__ f_w, const float* __restrict__ f_b2, const float* __restrict__ f_gamma,
    const float* __restrict__ f_beta, const float* __restrict__ f_mean, const float* __restrict__ f_var,
    const float* __restrict__ g_w, const float* __restrict__ g_b2, const float* __restrict__ g_gamma,
    const float* __restrict__ g_beta, const float* __restrict__ g_mean, const float* __restrict__ g_var,
    const float* __restrict__ h_w, const float* __restrict__ h_b2, const float* __restrict__ v_w,
    u16* __restrict__ Wb, u16* __restrict__ vwb, float* __restrict__ biasb)
{
  const int bid = blockIdx.x, t = threadIdx.x;
  if (bid < 768) {
    const int o = bid;
    const float* wsrc;
    float scale, bias_v;
    if (o < 256) {
      scale = f_gamma[o] * rsqrtf(f_var[o] + 1e-5f);
      wsrc = f_w + o * 512;
      bias_v = (f_b2[o] - f_mean[o]) * scale + f_beta[o];
    } else if (o < 512) {
      const int i = o - 256;
      scale = g_gamma[i] * rsqrtf(g_var[i] + 1e-5f);
      wsrc = g_w + i * 512;
      bias_v = (g_b2[i] - g_mean[i]) * scale + g_beta[i];
    } else {
      const int i = o - 512;
      scale = 1.0f;
      wsrc = h_w + i * 512;
      bias_v = h_b2[i];
    }
#pragma unroll
    for (int j = 0; j < 8; ++j)
      Wb[o * 512 + t * 8 + j] = f2bf(wsrc[t * 8 + j] * scale);
    if (t == 0) biasb[o] = bias_v;
  } else {
    const int r = bid - 768;
#pragma unroll
    for (int j = 0; j < 4; ++j)
      vwb[r * 256 + t * 4 + j] = f2bf(v_w[r * 256 + t * 4 + j]);
  }
}

// ---------------------------------------------------------------------------
// K1: x [b][c][n] f32  ->  xT [b*n][c] bf16   (64x64 tiles via LDS)
__global__ __launch_bounds__(256) void k_trx(const float* __restrict__ x, u16* __restrict__ xT)
{
  __shared__ __align__(16) u16 T[64 * 72];
  const int t = threadIdx.x;
  const int n0 = blockIdx.x * 64, c0 = blockIdx.y * 64, b = blockIdx.z;
#pragma unroll
  for (int it = 0; it < 4; ++it) {
    const int cr = it * 16 + (t >> 4);
    const int nc = (t & 15) * 4;
    const float4 v = *(const float4*)(x + ((size_t)(b * 512 + c0 + cr)) * N_ + n0 + nc);
    T[cr * 72 + nc + 0] = f2bf(v.x);
    T[cr * 72 + nc + 1] = f2bf(v.y);
    T[cr * 72 + nc + 2] = f2bf(v.z);
    T[cr * 72 + nc + 3] = f2bf(v.w);
  }
  __syncthreads();
#pragma unroll
  for (int it = 0; it < 2; ++it) {
    const int nr = it * 32 + (t >> 3);
    const int ch = t & 7;
    s16x8 val;
#pragma unroll
    for (int j = 0; j < 8; ++j) val[j] = (short)T[(ch * 8 + j) * 72 + nr];
    *(s16x8*)(xT + ((size_t)(b * N_ + n0 + nr)) * 512 + c0 + ch * 8) = val;
  }
}

// ---------------------------------------------------------------------------
// K2: GEMM1  D[o][n] = Wfgh[o][c] * x[c][n]  (+bias, relu for o<512)
//   XCD-grouped 1-D grid: the 6 mt-blocks sharing an xT tile have bids
//   congruent mod 8 -> same XCD L2 -> xT fetched once, not 6x.
__global__ __launch_bounds__(256) void k_gemm1(const u16* __restrict__ Wb, const u16* __restrict__ xT,
                                               const float* __restrict__ biasb,
                                               u16* __restrict__ fg, u16* __restrict__ hT)
{
  __shared__ __align__(16) u16 Al[128 * 64];
  __shared__ __align__(16) u16 Bl[128 * 64];
  const int tid = threadIdx.x, lane = tid & 63, w = tid >> 6;
  const int wr = w >> 1, wc = w & 1;
  const int row16 = lane & 15, g = lane >> 4;
  // bid = 48*chunk + 8*i6 + x8 ; nt = chunk*8 + x8 (XCD = x8), mt = i6
  const int bid = blockIdx.x;
  const int x8 = bid & 7;
  const int t6 = bid >> 3;
  const int mt = t6 % 6;
  const int nt = (t6 / 6) * 8 + x8;
  const int nbase = nt * 128;
  const int sr = lane >> 3, sj = lane & 7;

  f32x4 acc[4][4] = {};

  for (int kt = 0; kt < 8; ++kt) {
#pragma unroll
    for (int s = 0; s < 4; ++s) {
      const int r = s * 32 + w * 8 + sr;
      GLL16(Wb + (size_t)(mt * 128 + r) * 512 + kt * 64 + ((sj ^ (r & 7)) * 8), Al + (s * 32 + w * 8) * 64);
    }
#pragma unroll
    for (int s = 0; s < 4; ++s) {
      const int r = s * 32 + w * 8 + sr;
      GLL16(xT + (size_t)(nbase + r) * 512 + kt * 64 + ((sj ^ (r & 7)) * 8), Bl + (s * 32 + w * 8) * 64);
    }
    __syncthreads();
#pragma unroll
    for (int kk = 0; kk < 2; ++kk) {
      s16x8 a[4], b[4];
#pragma unroll
      for (int m = 0; m < 4; ++m) {
        const int row = wr * 64 + m * 16 + row16;
        a[m] = *(const s16x8*)(Al + row * 64 + (((kk * 4 + g) ^ (row & 7)) * 8));
      }
#pragma unroll
      for (int n = 0; n < 4; ++n) {
        const int row = wc * 64 + n * 16 + row16;
        b[n] = *(const s16x8*)(Bl + row * 64 + (((kk * 4 + g) ^ (row & 7)) * 8));
      }
#pragma unroll
      for (int m = 0; m < 4; ++m)
#pragma unroll
        for (int n = 0; n < 4; ++n)
          acc[m][n] = MFMA16(a[m], b[n], acc[m][n]);
    }
    __syncthreads();
  }

  const int bt = nbase / N_;
  if (mt < 4) {
#pragma unroll
    for (int m = 0; m < 4; ++m) {
      const int o0 = mt * 128 + wr * 64 + m * 16 + g * 4;
      const float b0 = biasb[o0], b1 = biasb[o0 + 1], b2 = biasb[o0 + 2], b3 = biasb[o0 + 3];
#pragma unroll
      for (int n = 0; n < 4; ++n) {
        const int nn = nbase + wc * 64 + n * 16 + row16;
        const f32x4 v = acc[m][n];
        *(ull*)(fg + (size_t)nn * 512 + o0) =
            pack4bf(fmaxf(v[0] + b0, 0.f), fmaxf(v[1] + b1, 0.f),
                    fmaxf(v[2] + b2, 0.f), fmaxf(v[3] + b3, 0.f));
      }
    }
  } else {
#pragma unroll
    for (int m = 0; m < 4; ++m) {
      const int o0 = mt * 128 + wr * 64 + m * 16 + g * 4;
#pragma unroll
      for (int n = 0; n < 4; ++n) {
        const int nn = nbase + wc * 64 + n * 16 + row16;
        const int nl = nn - bt * N_;
#pragma unroll
        for (int i = 0; i < 4; ++i)
          hT[(size_t)(bt * 256 + (o0 - 512) + i) * N_ + nl] = f2bf(acc[m][n][i] + biasb[o0 + i]);
      }
    }
  }
}

// ---------------------------------------------------------------------------
// K3: flash attention v4c — flash4 with (a) conflict-free 5-bit K swizzle
//   (K rows are 512B apart -> bank-0-aligned; 3-bit XOR left a 4-way
//   conflict among rows sharing row&7; full-width ch^row is bijective and
//   spreads each instruction across all 32 banks) and (b) P redistribution
//   via v_permlane32_swap_b32 (VALU) instead of 8 ds_bpermute shuffles.
__global__ __launch_bounds__(256, 2) void k_flash4(const u16* __restrict__ fg, const u16* __restrict__ hT,
                                                   u16* __restrict__ zp0, u16* __restrict__ zp1,
                                                   u16* __restrict__ zp2, u16* __restrict__ zp3,
                                                   float* __restrict__ dp)
{
  __shared__ __align__(16) u16 Sh[32768];   // 64KB: K[2]@0,8192  V[2]@16384,24576
  const int tid = threadIdx.x, lane = tid & 63, w = tid >> 6;
  const int q5 = lane & 31, hi = lane >> 5;

  // XCD-locality block swizzle: 1152 blocks; xcd = L&7 handles batches {2x,2x+1}
  const int L = blockIdx.x;
  const int xcd = L & 7, s = L >> 3;          // s 0..143
  const int b = xcd * 2 + (s >= 72 ? 1 : 0);
  const int j = (s >= 72) ? s - 72 : s;       // 0..71
  const int qb = (j % 18) * 128;
  const int sp = j / 18;                      // KV split id 0..3
  const int t0 = sp * 18;                     // first kv tile

  // Q fragments (B-operand): lane(q5,hi) holds Q[qrow][ks*16 + hi*8 .. +7]
  const int qrow = b * N_ + qb + w * 32 + q5;
  s16x8 qf[16];
#pragma unroll
  for (int ks = 0; ks < 16; ++ks)
    qf[ks] = *(const s16x8*)(fg + (size_t)qrow * 512 + ks * 16 + hi * 8);

  f32x16 accz[8] = {};     // z^T[c = ct*32 + rowpat][q = q5]
  float dsum = 0.f;

  // ---- staging helpers ----
  auto stageK = [&](int m0, int buf) {
    u16* dst = Sh + buf * 8192;
    const int kr = lane >> 5, kj = lane & 31;
#pragma unroll
    for (int s2 = 0; s2 < 4; ++s2) {
      const int i = w * 4 + s2;
      const int r = 2 * i + kr;                 // 0..31
      const int ch = kj ^ r;                    // 5-bit XOR (conflict-free)
      GLL16(fg + (size_t)(b * N_ + m0 + r) * 512 + 256 + ch * 8, dst + i * 512);
    }
  };
  auto stageV = [&](int m0, int buf) {
    u16* dst = Sh + 16384 + buf * 8192;
#pragma unroll
    for (int s2 = 0; s2 < 4; ++s2) {
      const int i = w * 4 + s2;
      const int r2 = i * 8 + (lane >> 3);
      const int ch = (lane & 7) ^ (r2 & 7);
      const int c = 2 * r2 + (ch >> 2);
      GLL16(hT + (size_t)(b * 256 + c) * N_ + m0 + (ch & 3) * 8, dst + i * 512);
    }
  };

  stageK(t0 * 32, 0);
  stageV(t0 * 32, 0);

  for (int it = 0; it < 18; ++it) {
    const int cur = it & 1;
    __syncthreads();                 // tile[cur] staged; prev readers of [cur^1] done
    if (it + 1 < 18) {               // prefetch next tile: full iteration to land
      stageK((t0 + it + 1) * 32, cur ^ 1);
      stageV((t0 + it + 1) * 32, cur ^ 1);
    }

    // ---- S^T[kv][q] = K * Q  (one 32x32 tile, K=256 in 16 steps)
    const u16* KL = Sh + cur * 8192;
    const int kvb = q5 * 256;        // A-row = kv = lane&31
    f32x16 sT = {};
    __builtin_amdgcn_s_setprio(1);
#pragma unroll
    for (int ks = 0; ks < 16; ++ks) {
      const int chp = (ks * 2 + hi) ^ q5;       // 5-bit XOR read
      const s16x8 kf = *(const s16x8*)(KL + kvb + chp * 8);
      sT = MFMA32(kf, qf[ks], sT);
    }
    __builtin_amdgcn_s_setprio(0);

    // ---- exp + in-register P packs
    u32 O[8];
    float lsum = 0.f;
#pragma unroll
    for (int m = 0; m < 4; ++m) {
      const float p0 = fexp2(sT[4 * m + 0] * K1F - K2F);
      const float p1 = fexp2(sT[4 * m + 1] * K1F - K2F);
      const float p2 = fexp2(sT[4 * m + 2] * K1F - K2F);
      const float p3 = fexp2(sT[4 * m + 3] * K1F - K2F);
      lsum += (p0 + p1) + (p2 + p3);
      O[2 * m] = pack2t(p0, p1);
      O[2 * m + 1] = pack2t(p2, p3);
    }
    dsum += lsum;

    // ---- P redistribution via permlane32_swap (VALU, no LDS port):
    //   swap(A,B): A' = [A.row0 | B.row0], B' = [A.row1 | B.row1]
    //   swap(O[4h], O[4h+2]) -> (wd0, wd2) of pf[h]; (O[4h+1],O[4h+3]) -> (wd1, wd3)
    u32 a0 = O[0], c0 = O[2];
    asm volatile("v_permlane32_swap_b32 %0, %1" : "+v"(a0), "+v"(c0));
    u32 a1 = O[1], c1 = O[3];
    asm volatile("v_permlane32_swap_b32 %0, %1" : "+v"(a1), "+v"(c1));
    u32 a2 = O[4], c2 = O[6];
    asm volatile("v_permlane32_swap_b32 %0, %1" : "+v"(a2), "+v"(c2));
    u32 a3 = O[5], c3 = O[7];
    asm volatile("v_permlane32_swap_b32 %0, %1" : "+v"(a3), "+v"(c3));

    s16x8 pf[2];
    {
      union { u32 wd[4]; s16x8 v; } u;
      u.wd[0] = a0; u.wd[1] = a1; u.wd[2] = c0; u.wd[3] = c1;
      pf[0] = u.v;
    }
    {
      union { u32 wd[4]; s16x8 v; } u;
      u.wd[0] = a2; u.wd[1] = a3; u.wd[2] = c2; u.wd[3] = c3;
      pf[1] = u.v;
    }

    // ---- PV: accz[ct] += V^T(c-rows) * P   (8 c-tiles x 2 k-halves)
    const u16* VL = Sh + 16384 + cur * 8192;
    __builtin_amdgcn_s_setprio(1);
#pragma unroll
    for (int h = 0; h < 2; ++h)
#pragma unroll
      for (int ct = 0; ct < 8; ++ct) {
        const int c = ct * 32 + q5;
        const int r2 = c >> 1;
        const int ch = (c & 1) * 4 + h * 2 + hi;
        const int chp = ch ^ (r2 & 7);
        const s16x8 vf = *(const s16x8*)(VL + r2 * 64 + chp * 8);
        accz[ct] = MFMA32(vf, pf[h], accz[ct]);
      }
    __builtin_amdgcn_s_setprio(0);
  }

  // ---- denominator: combine hi-halves; lane q (hi=0) stores
  const float dtot = dsum + (float)__shfl_xor(dsum, 32);
  if (hi == 0)
    dp[(size_t)sp * NT_ + b * N_ + qb + w * 32 + q5] = dtot;

  // ---- transpose z^T -> [n][c] via per-wave LDS region, coalesced store
  __syncthreads();                   // everyone done with K/V LDS
  u16* R = Sh + w * 8192;            // 16KB per wave: [32 n][256 c], quad-swz
#pragma unroll
  for (int ct = 0; ct < 8; ++ct)
#pragma unroll
    for (int m = 0; m < 4; ++m) {
      const int quad = ct * 8 + 2 * m + hi;       // c-quad index (c = quad*4..)
      const int pos = quad ^ (q5 & 7);
      *(ull*)(R + q5 * 256 + pos * 4) =
          pack4bf(accz[ct][4 * m + 0], accz[ct][4 * m + 1],
                  accz[ct][4 * m + 2], accz[ct][4 * m + 3]);
    }
  u16* zp = (sp < 2) ? (sp ? zp1 : zp0) : (sp == 2 ? zp2 : zp3);
  const size_t gbase = (size_t)(b * N_ + qb + w * 32) * 256;
#pragma unroll
  for (int n = 0; n < 32; ++n) {
    const ull v = *(const ull*)(R + n * 256 + ((lane ^ (n & 7)) & 63) * 4);
    *(ull*)(zp + gbase + n * 256 + lane * 4) = v;
  }
}

// ---------------------------------------------------------------------------
// K3b: combine partials (streaming BW op):  z = (sum_s zp_s) / (sum_s dp_s)
__global__ __launch_bounds__(256) void k_combine(const u16* __restrict__ zp0, const u16* __restrict__ zp1,
                                                 const u16* __restrict__ zp2, const u16* __restrict__ zp3,
                                                 const float* __restrict__ dp, u16* __restrict__ zout)
{
  const int gid = blockIdx.x * 256 + threadIdx.x;
  const int n = gid >> 6;
  const int c = (gid & 63) * 4;
  const float inv = 1.0f / (dp[n] + dp[NT_ + n] + dp[2 * NT_ + n] + dp[3 * NT_ + n]);
  const ull va = *(const ull*)(zp0 + (size_t)n * 256 + c);
  const ull vb = *(const ull*)(zp1 + (size_t)n * 256 + c);
  const ull vc = *(const ull*)(zp2 + (size_t)n * 256 + c);
  const ull vd = *(const ull*)(zp3 + (size_t)n * 256 + c);
  const float a0 = bf2f((u32)(va & 0xffff)) + bf2f((u32)(vb & 0xffff)) +
                   bf2f((u32)(vc & 0xffff)) + bf2f((u32)(vd & 0xffff));
  const float a1 = bf2f((u32)((va >> 16) & 0xffff)) + bf2f((u32)((vb >> 16) & 0xffff)) +
                   bf2f((u32)((vc >> 16) & 0xffff)) + bf2f((u32)((vd >> 16) & 0xffff));
  const float a2 = bf2f((u32)((va >> 32) & 0xffff)) + bf2f((u32)((vb >> 32) & 0xffff)) +
                   bf2f((u32)((vc >> 32) & 0xffff)) + bf2f((u32)((vd >> 32) & 0xffff));
  const float a3 = bf2f((u32)(va >> 48)) + bf2f((u32)(vb >> 48)) +
                   bf2f((u32)(vc >> 48)) + bf2f((u32)(vd >> 48));
  *(ull*)(zout + (size_t)n * 256 + c) = pack4bf(a0 * inv, a1 * inv, a2 * inv, a3 * inv);
}

// ---------------------------------------------------------------------------
// K4: GEMM2  out = v_w * z + v_b + x.  XCD-grouped 1-D grid: the 4 ot-blocks
//   sharing an nt-slice's z rows have bids congruent mod 8 -> same XCD L2.
__global__ __launch_bounds__(256) void k_gemm2(const u16* __restrict__ zb, const u16* __restrict__ vwb,
                                               const float* __restrict__ v_b, const float* __restrict__ x,
                                               float* __restrict__ out)
{
  __shared__ __align__(16) u16 Al[128 * 64];
  __shared__ __align__(16) u16 Bl[128 * 64];
  const int tid = threadIdx.x, lane = tid & 63, w = tid >> 6;
  const int wr = w >> 1, wc = w & 1;
  const int row16 = lane & 15, g = lane >> 4;
  // bid = 32*chunk + 8*ot + x8 ; nt = chunk*8 + x8 (XCD = x8)
  const int bid = blockIdx.x;
  const int x8 = bid & 7;
  const int t4 = bid >> 3;
  const int ot = t4 & 3;
  const int nt = (t4 >> 2) * 8 + x8;
  const int nbase = nt * 128;
  const int sr = lane >> 3, sj = lane & 7;

  f32x4 acc[4][4] = {};

  for (int kt = 0; kt < 4; ++kt) {
#pragma unroll
    for (int s = 0; s < 4; ++s) {
      const int r = s * 32 + w * 8 + sr;
      GLL16(zb + (size_t)(nbase + r) * 256 + kt * 64 + ((sj ^ (r & 7)) * 8), Al + (s * 32 + w * 8) * 64);
    }
#pragma unroll
    for (int s = 0; s < 4; ++s) {
      const int r = s * 32 + w * 8 + sr;
      GLL16(vwb + (size_t)(ot * 128 + r) * 256 + kt * 64 + ((sj ^ (r & 7)) * 8), Bl + (s * 32 + w * 8) * 64);
    }
    __syncthreads();
#pragma unroll
    for (int kk = 0; kk < 2; ++kk) {
      s16x8 a[4], b[4];
#pragma unroll
      for (int m = 0; m < 4; ++m) {
        const int row = wr * 64 + m * 16 + row16;
        a[m] = *(const s16x8*)(Al + row * 64 + (((kk * 4 + g) ^ (row & 7)) * 8));
      }
#pragma unroll
      for (int n = 0; n < 4; ++n) {
        const int row = wc * 64 + n * 16 + row16;
        b[n] = *(const s16x8*)(Bl + row * 64 + (((kk * 4 + g) ^ (row & 7)) * 8));
      }
#pragma unroll
      for (int m = 0; m < 4; ++m)
#pragma unroll
        for (int n = 0; n < 4; ++n)
          acc[m][n] = MFMA16(a[m], b[n], acc[m][n]);
    }
    __syncthreads();
  }

  const int bt = nbase / N_;
#pragma unroll
  for (int m = 0; m < 4; ++m) {
    const int nl0 = (nbase - bt * N_) + wr * 64 + m * 16 + g * 4;
#pragma unroll
    for (int n = 0; n < 4; ++n) {
      const int o = ot * 128 + wc * 64 + n * 16 + row16;
      const float vb = v_b[o];
      const size_t off = (size_t)(bt * 512 + o) * N_ + nl0;
      const float4 xv = *(const float4*)(x + off);
      float4 r;
      r.x = acc[m][n][0] + vb + xv.x;
      r.y = acc[m][n][1] + vb + xv.y;
      r.z = acc[m][n][2] + vb + xv.z;
      r.w = acc[m][n][3] + vb + xv.w;
      *(float4*)(out + off) = r;
    }
  }
}

// ---------------------------------------------------------------------------
extern "C" void kernel_launch(void* const* d_in, const int* in_sizes, int n_in,
                              void* d_out, int out_size, void* d_ws, size_t ws_size,
                              hipStream_t stream)
{
  const float* x       = (const float*)d_in[0];
  const float* f_w     = (const float*)d_in[1];
  const float* f_b     = (const float*)d_in[2];
  const float* f_gamma = (const float*)d_in[3];
  const float* f_beta  = (const float*)d_in[4];
  const float* f_mean  = (const float*)d_in[5];
  const float* f_var   = (const float*)d_in[6];
  const float* g_w     = (const float*)d_in[7];
  const float* g_b     = (const float*)d_in[8];
  const float* g_gamma = (const float*)d_in[9];
  const float* g_beta  = (const float*)d_in[10];
  const float* g_mean  = (const float*)d_in[11];
  const float* g_var   = (const float*)d_in[12];
  const float* h_w     = (const float*)d_in[13];
  const float* h_b     = (const float*)d_in[14];
  const float* v_w     = (const float*)d_in[15];
  const float* v_b     = (const float*)d_in[16];

  char* ws = (char*)d_ws;
  u16*  xT    = (u16*)(ws + OFF_XT);
  u16*  fg    = (u16*)(ws + OFF_FG);
  u16*  hT    = (u16*)(ws + OFF_HT);
  u16*  Wb    = (u16*)(ws + OFF_WB);
  u16*  vwb   = (u16*)(ws + OFF_VW);
  float* biasb = (float*)(ws + OFF_BIAS);
  float* out  = (float*)d_out;

  // flash partials: splits 0,1 over the dead xT region; splits 2,3 and the
  // denominators in d_out (fully overwritten by k_gemm2 afterwards).
  u16*  zp0 = (u16*)(ws + OFF_XT);
  u16*  zp1 = (u16*)(ws + OFF_XT + 2 * ZP_ELEMS);       // byte offset = 2B*elems
  u16*  zp2 = (u16*)d_out;
  u16*  zp3 = (u16*)d_out + ZP_ELEMS;
  float* dp = (float*)((char*)d_out + 4 * ZP_ELEMS);    // 4*NT_ floats
  u16*  z   = (u16*)(ws + OFF_FG);   // combined z overwrites dead fg region

  hipLaunchKernelGGL(k_prep, dim3(1280), dim3(64), 0, stream,
                     f_w, f_b, f_gamma, f_beta, f_mean, f_var,
                     g_w, g_b, g_gamma, g_beta, g_mean, g_var,
                     h_w, h_b, v_w, Wb, vwb, biasb);
  hipLaunchKernelGGL(k_trx, dim3(36, 8, 16), dim3(256), 0, stream, x, xT);
  hipLaunchKernelGGL(k_gemm1, dim3(1728), dim3(256), 0, stream, Wb, xT, biasb, fg, hT);
  hipLaunchKernelGGL(k_flash4, dim3(1152), dim3(256), 0, stream, fg, hT, zp0, zp1, zp2, zp3, dp);
  hipLaunchKernelGGL(k_combine, dim3(9216), dim3(256), 0, stream, zp0, zp1, zp2, zp3, dp, z);
  hipLaunchKernelGGL(k_gemm2, dim3(1152), dim3(256), 0, stream, z, vwb, v_b, x, out);
}

// Round 11
// 277.128 us; speedup vs baseline: 1.0333x; 1.0333x over previous
//
#include <hip/hip_runtime.h>

// ---------------------------------------------------------------------------
// SOABlock: f,g = BN(ReLU(1x1conv)), h = 1x1conv, attn = softmax(f^T g /16),
// z = attn @ h^T, out = v(z) + x.   B=16, C=512, MID=256, N=48*48=2304.
// ---------------------------------------------------------------------------

#define B_    16
#define C_    512
#define MID_  256
#define N_    2304
#define NT_   (B_ * N_)          // 36864

typedef unsigned short u16;
typedef unsigned int   u32;
typedef unsigned long long ull;
typedef short s16x8 __attribute__((ext_vector_type(8)));   // 8 bf16 (4 VGPR)
typedef float f32x4 __attribute__((ext_vector_type(4)));
typedef float f32x16 __attribute__((ext_vector_type(16)));

// exp constants: P = exp(S/16 - 20) = exp2(S*K1F - K2F)
#define K1F 0.09016844005556021f
#define K2F 28.853900817779268f

#define MFMA16(a, b, c) __builtin_amdgcn_mfma_f32_16x16x32_bf16(a, b, c, 0, 0, 0)
#define MFMA32(a, b, c) __builtin_amdgcn_mfma_f32_32x32x16_bf16(a, b, c, 0, 0, 0)

__device__ __forceinline__ u16 f2bf(float f) {
  unsigned int u = __float_as_uint(f);
  return (u16)((u + 0x7FFFu + ((u >> 16) & 1u)) >> 16);
}
__device__ __forceinline__ u32 pack2bf(float a, float b) {
  return (u32)f2bf(a) | ((u32)f2bf(b) << 16);
}
__device__ __forceinline__ ull pack4bf(float a, float b, float c, float d) {
  return (ull)pack2bf(a, b) | ((ull)pack2bf(c, d) << 32);
}
// truncating pack (P values; ~0.2% bias is fine, saves VALU)
__device__ __forceinline__ u32 pack2t(float a, float b) {
  return (__float_as_uint(a) >> 16) | (__float_as_uint(b) & 0xffff0000u);
}
__device__ __forceinline__ float bf2f(u32 v) { return __uint_as_float(v << 16); }
// single-instruction 2^x (avoids libm exp2f guard code in the softmax chain)
__device__ __forceinline__ float fexp2(float x) {
  float r;
  asm("v_exp_f32 %0, %1" : "=v"(r) : "v"(x));
  return r;
}

#define GLL16(src, dst)                                                        \
  __builtin_amdgcn_global_load_lds(                                            \
      (const __attribute__((address_space(1))) void*)(src),                    \
      (__attribute__((address_space(3))) void*)(dst), 16, 0, 0)

// ---------------------------------------------------------------------------
// ws layout (bytes)
#define OFF_XT   0ull            // xT bf16 [36864][512]; later zp splits 0,1
#define OFF_FG   37748736ull     // fg bf16 [36864][512]; later combined z bf16
#define OFF_HT   75497472ull     // hT bf16 [16][256][2304]
#define OFF_WB   94371840ull     // Wfgh bf16 [768][512]
#define OFF_VW   95158272ull     // v_w bf16 [512][256]
#define OFF_BIAS 95420416ull     // bias f32 [768]
#define ZP_ELEMS (9437184ull)    // 36864*256 per split

// ---------------------------------------------------------------------------
// K0: fold BN into conv weights, convert weights to bf16.
__global__ __launch_bounds__(64) void k_prep(
    const float* __restrict__ f_w, const float* __restrict__ f_b2, const float* __restrict__ f_gamma,
    const float* __restrict__ f_beta, const float* __restrict__ f_mean, const float* __restrict__ f_var,
    const float* __restrict__ g_w, const float* __restrict__ g_b2, const float* __restrict__ g_gamma,
    const float* __restrict__ g_beta, const float* __restrict__ g_mean, const float* __restrict__ g_var,
    const float* __restrict__ h_w, const float* __restrict__ h_b2, const float* __restrict__ v_w,
    u16* __restrict__ Wb, u16* __restrict__ vwb, float* __restrict__ biasb)
{
  const int bid = blockIdx.x, t = threadIdx.x;
  if (bid < 768) {
    const int o = bid;
    const float* wsrc;
    float scale, bias_v;
    if (o < 256) {
      scale = f_gamma[o] * rsqrtf(f_var[o] + 1e-5f);
      wsrc = f_w + o * 512;
      bias_v = (f_b2[o] - f_mean[o]) * scale + f_beta[o];
    } else if (o < 512) {
      const int i = o - 256;
      scale = g_gamma[i] * rsqrtf(g_var[i] + 1e-5f);
      wsrc = g_w + i * 512;
      bias_v = (g_b2[i] - g_mean[i]) * scale + g_beta[i];
    } else {
      const int i = o - 512;
      scale = 1.0f;
      wsrc = h_w + i * 512;
      bias_v = h_b2[i];
    }
#pragma unroll
    for (int j = 0; j < 8; ++j)
      Wb[o * 512 + t * 8 + j] = f2bf(wsrc[t * 8 + j] * scale);
    if (t == 0) biasb[o] = bias_v;
  } else {
    const int r = bid - 768;
#pragma unroll
    for (int j = 0; j < 4; ++j)
      vwb[r * 256 + t * 4 + j] = f2bf(v_w[r * 256 + t * 4 + j]);
  }
}

// ---------------------------------------------------------------------------
// K1: x [b][c][n] f32  ->  xT [b*n][c] bf16   (64x64 tiles via LDS)
__global__ __launch_bounds__(256) void k_trx(const float* __restrict__ x, u16* __restrict__ xT)
{
  __shared__ __align__(16) u16 T[64 * 72];
  const int t = threadIdx.x;
  const int n0 = blockIdx.x * 64, c0 = blockIdx.y * 64, b = blockIdx.z;
#pragma unroll
  for (int it = 0; it < 4; ++it) {
    const int cr = it * 16 + (t >> 4);
    const int nc = (t & 15) * 4;
    const float4 v = *(const float4*)(x + ((size_t)(b * 512 + c0 + cr)) * N_ + n0 + nc);
    T[cr * 72 + nc + 0] = f2bf(v.x);
    T[cr * 72 + nc + 1] = f2bf(v.y);
    T[cr * 72 + nc + 2] = f2bf(v.z);
    T[cr * 72 + nc + 3] = f2bf(v.w);
  }
  __syncthreads();
#pragma unroll
  for (int it = 0; it < 2; ++it) {
    const int nr = it * 32 + (t >> 3);
    const int ch = t & 7;
    s16x8 val;
#pragma unroll
    for (int j = 0; j < 8; ++j) val[j] = (short)T[(ch * 8 + j) * 72 + nr];
    *(s16x8*)(xT + ((size_t)(b * N_ + n0 + nr)) * 512 + c0 + ch * 8) = val;
  }
}

// ---------------------------------------------------------------------------
// K2: GEMM1  D[o][n] = Wfgh[o][c] * x[c][n]  (+bias, relu for o<512)
//   XCD-grouped 1-D grid: the 6 mt-blocks sharing an xT tile have bids
//   congruent mod 8 -> same XCD L2 -> xT fetched once, not 6x.
__global__ __launch_bounds__(256) void k_gemm1(const u16* __restrict__ Wb, const u16* __restrict__ xT,
                                               const float* __restrict__ biasb,
                                               u16* __restrict__ fg, u16* __restrict__ hT)
{
  __shared__ __align__(16) u16 Al[128 * 64];
  __shared__ __align__(16) u16 Bl[128 * 64];
  const int tid = threadIdx.x, lane = tid & 63, w = tid >> 6;
  const int wr = w >> 1, wc = w & 1;
  const int row16 = lane & 15, g = lane >> 4;
  // bid = 48*chunk + 8*i6 + x8 ; nt = chunk*8 + x8 (XCD = x8), mt = i6
  const int bid = blockIdx.x;
  const int x8 = bid & 7;
  const int t6 = bid >> 3;
  const int mt = t6 % 6;
  const int nt = (t6 / 6) * 8 + x8;
  const int nbase = nt * 128;
  const int sr = lane >> 3, sj = lane & 7;

  f32x4 acc[4][4] = {};

  for (int kt = 0; kt < 8; ++kt) {
#pragma unroll
    for (int s = 0; s < 4; ++s) {
      const int r = s * 32 + w * 8 + sr;
      GLL16(Wb + (size_t)(mt * 128 + r) * 512 + kt * 64 + ((sj ^ (r & 7)) * 8), Al + (s * 32 + w * 8) * 64);
    }
#pragma unroll
    for (int s = 0; s < 4; ++s) {
      const int r = s * 32 + w * 8 + sr;
      GLL16(xT + (size_t)(nbase + r) * 512 + kt * 64 + ((sj ^ (r & 7)) * 8), Bl + (s * 32 + w * 8) * 64);
    }
    __syncthreads();
#pragma unroll
    for (int kk = 0; kk < 2; ++kk) {
      s16x8 a[4], b[4];
#pragma unroll
      for (int m = 0; m < 4; ++m) {
        const int row = wr * 64 + m * 16 + row16;
        a[m] = *(const s16x8*)(Al + row * 64 + (((kk * 4 + g) ^ (row & 7)) * 8));
      }
#pragma unroll
      for (int n = 0; n < 4; ++n) {
        const int row = wc * 64 + n * 16 + row16;
        b[n] = *(const s16x8*)(Bl + row * 64 + (((kk * 4 + g) ^ (row & 7)) * 8));
      }
#pragma unroll
      for (int m = 0; m < 4; ++m)
#pragma unroll
        for (int n = 0; n < 4; ++n)
          acc[m][n] = MFMA16(a[m], b[n], acc[m][n]);
    }
    __syncthreads();
  }

  const int bt = nbase / N_;
  if (mt < 4) {
#pragma unroll
    for (int m = 0; m < 4; ++m) {
      const int o0 = mt * 128 + wr * 64 + m * 16 + g * 4;
      const float b0 = biasb[o0], b1 = biasb[o0 + 1], b2 = biasb[o0 + 2], b3 = biasb[o0 + 3];
#pragma unroll
      for (int n = 0; n < 4; ++n) {
        const int nn = nbase + wc * 64 + n * 16 + row16;
        const f32x4 v = acc[m][n];
        *(ull*)(fg + (size_t)nn * 512 + o0) =
            pack4bf(fmaxf(v[0] + b0, 0.f), fmaxf(v[1] + b1, 0.f),
                    fmaxf(v[2] + b2, 0.f), fmaxf(v[3] + b3, 0.f));
      }
    }
  } else {
#pragma unroll
    for (int m = 0; m < 4; ++m) {
      const int o0 = mt * 128 + wr * 64 + m * 16 + g * 4;
#pragma unroll
      for (int n = 0; n < 4; ++n) {
        const int nn = nbase + wc * 64 + n * 16 + row16;
        const int nl = nn - bt * N_;
#pragma unroll
        for (int i = 0; i < 4; ++i)
          hT[(size_t)(bt * 256 + (o0 - 512) + i) * N_ + nl] = f2bf(acc[m][n][i] + biasb[o0 + i]);
      }
    }
  }
}

// ---------------------------------------------------------------------------
// K3: flash attention v4 (round-9 proven version, verbatim).  128 q/block,
//   4 waves x 32 q; KV tile 32, K/V double-buffered, ONE barrier per iter,
//   in-register P via mfma32(K,Q) + shfl_xor(32); KV split 4-way.
__global__ __launch_bounds__(256, 2) void k_flash4(const u16* __restrict__ fg, const u16* __restrict__ hT,
                                                   u16* __restrict__ zp0, u16* __restrict__ zp1,
                                                   u16* __restrict__ zp2, u16* __restrict__ zp3,
                                                   float* __restrict__ dp)
{
  __shared__ __align__(16) u16 Sh[32768];   // 64KB: K[2]@0,8192  V[2]@16384,24576
  const int tid = threadIdx.x, lane = tid & 63, w = tid >> 6;
  const int q5 = lane & 31, hi = lane >> 5;

  // XCD-locality block swizzle: 1152 blocks; xcd = L&7 handles batches {2x,2x+1}
  const int L = blockIdx.x;
  const int xcd = L & 7, s = L >> 3;          // s 0..143
  const int b = xcd * 2 + (s >= 72 ? 1 : 0);
  const int j = (s >= 72) ? s - 72 : s;       // 0..71
  const int qb = (j % 18) * 128;
  const int sp = j / 18;                      // KV split id 0..3
  const int t0 = sp * 18;                     // first kv tile

  // Q fragments (B-operand): lane(q5,hi) holds Q[qrow][ks*16 + hi*8 .. +7]
  const int qrow = b * N_ + qb + w * 32 + q5;
  s16x8 qf[16];
#pragma unroll
  for (int ks = 0; ks < 16; ++ks)
    qf[ks] = *(const s16x8*)(fg + (size_t)qrow * 512 + ks * 16 + hi * 8);

  f32x16 accz[8] = {};     // z^T[c = ct*32 + rowpat][q = q5]
  float dsum = 0.f;

  // ---- staging helpers ----
  auto stageK = [&](int m0, int buf) {
    u16* dst = Sh + buf * 8192;
    const int kr = lane >> 5, kj = lane & 31;
#pragma unroll
    for (int s2 = 0; s2 < 4; ++s2) {
      const int i = w * 4 + s2;
      const int r = 2 * i + kr;
      const int ch = (kj & 24) | ((kj ^ (r & 7)) & 7);
      GLL16(fg + (size_t)(b * N_ + m0 + r) * 512 + 256 + ch * 8, dst + i * 512);
    }
  };
  auto stageV = [&](int m0, int buf) {
    u16* dst = Sh + 16384 + buf * 8192;
#pragma unroll
    for (int s2 = 0; s2 < 4; ++s2) {
      const int i = w * 4 + s2;
      const int r2 = i * 8 + (lane >> 3);
      const int ch = (lane & 7) ^ (r2 & 7);
      const int c = 2 * r2 + (ch >> 2);
      GLL16(hT + (size_t)(b * 256 + c) * N_ + m0 + (ch & 3) * 8, dst + i * 512);
    }
  };

  stageK(t0 * 32, 0);
  stageV(t0 * 32, 0);

  for (int it = 0; it < 18; ++it) {
    const int cur = it & 1;
    __syncthreads();                 // tile[cur] staged; prev readers of [cur^1] done
    if (it + 1 < 18) {               // prefetch next tile: full iteration to land
      stageK((t0 + it + 1) * 32, cur ^ 1);
      stageV((t0 + it + 1) * 32, cur ^ 1);
    }

    // ---- S^T[kv][q] = K * Q  (one 32x32 tile, K=256 in 16 steps)
    const u16* KL = Sh + cur * 8192;
    const int kvb = q5 * 256;        // A-row = kv = lane&31
    f32x16 sT = {};
    __builtin_amdgcn_s_setprio(1);
#pragma unroll
    for (int ks = 0; ks < 16; ++ks) {
      const int ch = ks * 2 + hi;
      const int chp = (ch & 24) | ((ch ^ (q5 & 7)) & 7);
      const s16x8 kf = *(const s16x8*)(KL + kvb + chp * 8);
      sT = MFMA32(kf, qf[ks], sT);
    }
    __builtin_amdgcn_s_setprio(0);

    // ---- exp + in-register P packs;  own quads O[2m+j], partner X via shfl
    u32 O[8], X[8];
    float lsum = 0.f;
#pragma unroll
    for (int m = 0; m < 4; ++m) {
      const float p0 = fexp2(sT[4 * m + 0] * K1F - K2F);
      const float p1 = fexp2(sT[4 * m + 1] * K1F - K2F);
      const float p2 = fexp2(sT[4 * m + 2] * K1F - K2F);
      const float p3 = fexp2(sT[4 * m + 3] * K1F - K2F);
      lsum += (p0 + p1) + (p2 + p3);
      O[2 * m] = pack2t(p0, p1);
      O[2 * m + 1] = pack2t(p2, p3);
    }
    dsum += lsum;
#pragma unroll
    for (int r = 0; r < 8; ++r) X[r] = (u32)__shfl_xor((int)O[r], 32);

    s16x8 pf[2];
#pragma unroll
    for (int h = 0; h < 2; ++h) {
      union { u32 wd[4]; s16x8 v; } u;
      u.wd[0] = hi ? X[4 * h + 2] : O[4 * h + 0];
      u.wd[1] = hi ? X[4 * h + 3] : O[4 * h + 1];
      u.wd[2] = hi ? O[4 * h + 2] : X[4 * h + 0];
      u.wd[3] = hi ? O[4 * h + 3] : X[4 * h + 1];
      pf[h] = u.v;
    }

    // ---- PV: accz[ct] += V^T(c-rows) * P   (8 c-tiles x 2 k-halves)
    const u16* VL = Sh + 16384 + cur * 8192;
    __builtin_amdgcn_s_setprio(1);
#pragma unroll
    for (int h = 0; h < 2; ++h)
#pragma unroll
      for (int ct = 0; ct < 8; ++ct) {
        const int c = ct * 32 + q5;
        const int r2 = c >> 1;
        const int ch = (c & 1) * 4 + h * 2 + hi;
        const int chp = ch ^ (r2 & 7);
        const s16x8 vf = *(const s16x8*)(VL + r2 * 64 + chp * 8);
        accz[ct] = MFMA32(vf, pf[h], accz[ct]);
      }
    __builtin_amdgcn_s_setprio(0);
  }

  // ---- denominator: combine hi-halves; lane q (hi=0) stores
  const float dtot = dsum + (float)__shfl_xor(dsum, 32);
  if (hi == 0)
    dp[(size_t)sp * NT_ + b * N_ + qb + w * 32 + q5] = dtot;

  // ---- transpose z^T -> [n][c] via per-wave LDS region, coalesced store
  __syncthreads();                   // everyone done with K/V LDS
  u16* R = Sh + w * 8192;            // 16KB per wave: [32 n][256 c], quad-swz
#pragma unroll
  for (int ct = 0; ct < 8; ++ct)
#pragma unroll
    for (int m = 0; m < 4; ++m) {
      const int quad = ct * 8 + 2 * m + hi;       // c-quad index (c = quad*4..)
      const int pos = quad ^ (q5 & 7);
      *(ull*)(R + q5 * 256 + pos * 4) =
          pack4bf(accz[ct][4 * m + 0], accz[ct][4 * m + 1],
                  accz[ct][4 * m + 2], accz[ct][4 * m + 3]);
    }
  u16* zp = (sp < 2) ? (sp ? zp1 : zp0) : (sp == 2 ? zp2 : zp3);
  const size_t gbase = (size_t)(b * N_ + qb + w * 32) * 256;
#pragma unroll
  for (int n = 0; n < 32; ++n) {
    const ull v = *(const ull*)(R + n * 256 + ((lane ^ (n & 7)) & 63) * 4);
    *(ull*)(zp + gbase + n * 256 + lane * 4) = v;
  }
}

// ---------------------------------------------------------------------------
// K3b: combine partials (streaming BW op, 16B/lane):
//   z = (sum_s zp_s) / (sum_s dp_s)
__global__ __launch_bounds__(256) void k_combine(const u16* __restrict__ zp0, const u16* __restrict__ zp1,
                                                 const u16* __restrict__ zp2, const u16* __restrict__ zp3,
                                                 const float* __restrict__ dp, u16* __restrict__ zout)
{
  const int gid = blockIdx.x * 256 + threadIdx.x;
  const int n = gid >> 5;
  const int c = (gid & 31) * 8;
  const float inv = 1.0f / (dp[n] + dp[NT_ + n] + dp[2 * NT_ + n] + dp[3 * NT_ + n]);
  const size_t off = (size_t)n * 256 + c;
  const s16x8 pa = *(const s16x8*)(zp0 + off);
  const s16x8 pb = *(const s16x8*)(zp1 + off);
  const s16x8 pc = *(const s16x8*)(zp2 + off);
  const s16x8 pd = *(const s16x8*)(zp3 + off);
  union { u32 wd[4]; s16x8 v; } u;
#pragma unroll
  for (int q = 0; q < 4; ++q) {
    const float e0 = (bf2f((u16)pa[2 * q]) + bf2f((u16)pb[2 * q]) +
                      bf2f((u16)pc[2 * q]) + bf2f((u16)pd[2 * q])) * inv;
    const float e1 = (bf2f((u16)pa[2 * q + 1]) + bf2f((u16)pb[2 * q + 1]) +
                      bf2f((u16)pc[2 * q + 1]) + bf2f((u16)pd[2 * q + 1])) * inv;
    u.wd[q] = pack2bf(e0, e1);
  }
  *(s16x8*)(zout + off) = u.v;
}

// ---------------------------------------------------------------------------
// K4: GEMM2  out = v_w * z + v_b + x.  XCD-grouped 1-D grid: the 4 ot-blocks
//   sharing an nt-slice's z rows have bids congruent mod 8 -> same XCD L2.
__global__ __launch_bounds__(256) void k_gemm2(const u16* __restrict__ zb, const u16* __restrict__ vwb,
                                               const float* __restrict__ v_b, const float* __restrict__ x,
                                               float* __restrict__ out)
{
  __shared__ __align__(16) u16 Al[128 * 64];
  __shared__ __align__(16) u16 Bl[128 * 64];
  const int tid = threadIdx.x, lane = tid & 63, w = tid >> 6;
  const int wr = w >> 1, wc = w & 1;
  const int row16 = lane & 15, g = lane >> 4;
  // bid = 32*chunk + 8*ot + x8 ; nt = chunk*8 + x8 (XCD = x8)
  const int bid = blockIdx.x;
  const int x8 = bid & 7;
  const int t4 = bid >> 3;
  const int ot = t4 & 3;
  const int nt = (t4 >> 2) * 8 + x8;
  const int nbase = nt * 128;
  const int sr = lane >> 3, sj = lane & 7;

  f32x4 acc[4][4] = {};

  for (int kt = 0; kt < 4; ++kt) {
#pragma unroll
    for (int s = 0; s < 4; ++s) {
      const int r = s * 32 + w * 8 + sr;
      GLL16(zb + (size_t)(nbase + r) * 256 + kt * 64 + ((sj ^ (r & 7)) * 8), Al + (s * 32 + w * 8) * 64);
    }
#pragma unroll
    for (int s = 0; s < 4; ++s) {
      const int r = s * 32 + w * 8 + sr;
      GLL16(vwb + (size_t)(ot * 128 + r) * 256 + kt * 64 + ((sj ^ (r & 7)) * 8), Bl + (s * 32 + w * 8) * 64);
    }
    __syncthreads();
#pragma unroll
    for (int kk = 0; kk < 2; ++kk) {
      s16x8 a[4], b[4];
#pragma unroll
      for (int m = 0; m < 4; ++m) {
        const int row = wr * 64 + m * 16 + row16;
        a[m] = *(const s16x8*)(Al + row * 64 + (((kk * 4 + g) ^ (row & 7)) * 8));
      }
#pragma unroll
      for (int n = 0; n < 4; ++n) {
        const int row = wc * 64 + n * 16 + row16;
        b[n] = *(const s16x8*)(Bl + row * 64 + (((kk * 4 + g) ^ (row & 7)) * 8));
      }
#pragma unroll
      for (int m = 0; m < 4; ++m)
#pragma unroll
        for (int n = 0; n < 4; ++n)
          acc[m][n] = MFMA16(a[m], b[n], acc[m][n]);
    }
    __syncthreads();
  }

  const int bt = nbase / N_;
#pragma unroll
  for (int m = 0; m < 4; ++m) {
    const int nl0 = (nbase - bt * N_) + wr * 64 + m * 16 + g * 4;
#pragma unroll
    for (int n = 0; n < 4; ++n) {
      const int o = ot * 128 + wc * 64 + n * 16 + row16;
      const float vb = v_b[o];
      const size_t off = (size_t)(bt * 512 + o) * N_ + nl0;
      const float4 xv = *(const float4*)(x + off);
      float4 r;
      r.x = acc[m][n][0] + vb + xv.x;
      r.y = acc[m][n][1] + vb + xv.y;
      r.z = acc[m][n][2] + vb + xv.z;
      r.w = acc[m][n][3] + vb + xv.w;
      *(float4*)(out + off) = r;
    }
  }
}

// ---------------------------------------------------------------------------
extern "C" void kernel_launch(void* const* d_in, const int* in_sizes, int n_in,
                              void* d_out, int out_size, void* d_ws, size_t ws_size,
                              hipStream_t stream)
{
  const float* x       = (const float*)d_in[0];
  const float* f_w     = (const float*)d_in[1];
  const float* f_b     = (const float*)d_in[2];
  const float* f_gamma = (const float*)d_in[3];
  const float* f_beta  = (const float*)d_in[4];
  const float* f_mean  = (const float*)d_in[5];
  const float* f_var   = (const float*)d_in[6];
  const float* g_w     = (const float*)d_in[7];
  const float* g_b     = (const float*)d_in[8];
  const float* g_gamma = (const float*)d_in[9];
  const float* g_beta  = (const float*)d_in[10];
  const float* g_mean  = (const float*)d_in[11];
  const float* g_var   = (const float*)d_in[12];
  const float* h_w     = (const float*)d_in[13];
  const float* h_b     = (const float*)d_in[14];
  const float* v_w     = (const float*)d_in[15];
  const float* v_b     = (const float*)d_in[16];

  char* ws = (char*)d_ws;
  u16*  xT    = (u16*)(ws + OFF_XT);
  u16*  fg    = (u16*)(ws + OFF_FG);
  u16*  hT    = (u16*)(ws + OFF_HT);
  u16*  Wb    = (u16*)(ws + OFF_WB);
  u16*  vwb   = (u16*)(ws + OFF_VW);
  float* biasb = (float*)(ws + OFF_BIAS);
  float* out  = (float*)d_out;

  // flash partials: splits 0,1 over the dead xT region; splits 2,3 and the
  // denominators in d_out (fully overwritten by k_gemm2 afterwards).
  u16*  zp0 = (u16*)(ws + OFF_XT);
  u16*  zp1 = (u16*)(ws + OFF_XT + 2 * ZP_ELEMS);       // byte offset = 2B*elems
  u16*  zp2 = (u16*)d_out;
  u16*  zp3 = (u16*)d_out + ZP_ELEMS;
  float* dp = (float*)((char*)d_out + 4 * ZP_ELEMS);    // 4*NT_ floats
  u16*  z   = (u16*)(ws + OFF_FG);   // combined z overwrites dead fg region

  hipLaunchKernelGGL(k_prep, dim3(1280), dim3(64), 0, stream,
                     f_w, f_b, f_gamma, f_beta, f_mean, f_var,
                     g_w, g_b, g_gamma, g_beta, g_mean, g_var,
                     h_w, h_b, v_w, Wb, vwb, biasb);
  hipLaunchKernelGGL(k_trx, dim3(36, 8, 16), dim3(256), 0, stream, x, xT);
  hipLaunchKernelGGL(k_gemm1, dim3(1728), dim3(256), 0, stream, Wb, xT, biasb, fg, hT);
  hipLaunchKernelGGL(k_flash4, dim3(1152), dim3(256), 0, stream, fg, hT, zp0, zp1, zp2, zp3, dp);
  hipLaunchKernelGGL(k_combine, dim3(4608), dim3(256), 0, stream, zp0, zp1, zp2, zp3, dp, z);
  hipLaunchKernelGGL(k_gemm2, dim3(1152), dim3(256), 0, stream, z, vwb, v_b, x, out);
}